// Round 1
// baseline (1525.822 us; speedup 1.0000x reference)
//
#include <hip/hip_runtime.h>
#include <math.h>

#define SQ2PI 0.79788456f
#define H 512
#define MB 512
#define DIN 784
#define XCOV_ELEMS ((size_t)MB * H * H)

// m = 2*sigmoid(w)-1 = tanh(w/2); c[j] = sum_i (1 - m[i][j]^2)
__global__ __launch_bounds__(256) void wtrans_k(const float* __restrict__ w,
                                                float* __restrict__ m,
                                                float* __restrict__ c,
                                                int rows) {
    int j = blockIdx.x * 256 + threadIdx.x;  // column 0..511
    if (j >= H) return;
    float acc = 0.f;
    for (int i = 0; i < rows; ++i) {
        float v = tanhf(0.5f * w[i * H + j]);
        m[i * H + j] = v;
        acc += 1.f - v * v;
    }
    c[j] = acc;
}

// out[r][c] = tanh(SQ2PI * (A@W + th) * rsqrt( (FIRST? 0 : (1-Dsrc^2)@W^2) + csum ))
// A: M x K, Dsrc: M x K (ignored if FIRST), W: K x 512
template <bool FIRST>
__global__ __launch_bounds__(256) void layer_k(const float* __restrict__ A,
                                               const float* __restrict__ Dsrc,
                                               const float* __restrict__ W,
                                               const float* __restrict__ csum,
                                               const float* __restrict__ th,
                                               float* __restrict__ out,
                                               int K) {
    __shared__ __align__(16) float As[16][64];
    __shared__ __align__(16) float Ds[16][64];
    __shared__ __align__(16) float Bs[16][64];
    __shared__ __align__(16) float B2s[16][64];

    const int tid = threadIdx.x;
    const int tx = tid & 15;          // col group
    const int ty = tid >> 4;          // row group
    const int rowb = blockIdx.y * 64;
    const int colb = blockIdx.x * 64;

    float acc1[4][4] = {};
    float acc2[4][4] = {};

    const int lrow = tid >> 2;        // 0..63
    const int kseg = (tid & 3) * 4;   // 0,4,8,12

    for (int k0 = 0; k0 < K; k0 += 16) {
        // stage A tile (64 rows x 16 k), kk-major in LDS
        float4 av = *(const float4*)&A[(size_t)(rowb + lrow) * K + k0 + kseg];
        As[kseg + 0][lrow] = av.x;
        As[kseg + 1][lrow] = av.y;
        As[kseg + 2][lrow] = av.z;
        As[kseg + 3][lrow] = av.w;
        if (!FIRST) {
            float4 dv = *(const float4*)&Dsrc[(size_t)(rowb + lrow) * K + k0 + kseg];
            Ds[kseg + 0][lrow] = 1.f - dv.x * dv.x;
            Ds[kseg + 1][lrow] = 1.f - dv.y * dv.y;
            Ds[kseg + 2][lrow] = 1.f - dv.z * dv.z;
            Ds[kseg + 3][lrow] = 1.f - dv.w * dv.w;
        }
        // stage W tile (16 k x 64 cols) + squared copy
#pragma unroll
        for (int i = 0; i < 4; ++i) {
            int e = tid + i * 256;
            int kk = e >> 6, col = e & 63;
            float v = W[(size_t)(k0 + kk) * H + colb + col];
            Bs[kk][col] = v;
            B2s[kk][col] = v * v;
        }
        __syncthreads();

#pragma unroll
        for (int kk = 0; kk < 16; ++kk) {
            float4 a = *(const float4*)&As[kk][ty * 4];
            float4 b = *(const float4*)&Bs[kk][tx * 4];
            float4 b2 = *(const float4*)&B2s[kk][tx * 4];
            float av4[4] = {a.x, a.y, a.z, a.w};
            float bv4[4] = {b.x, b.y, b.z, b.w};
            float b2v4[4] = {b2.x, b2.y, b2.z, b2.w};
            float dv4[4];
            if (!FIRST) {
                float4 d = *(const float4*)&Ds[kk][ty * 4];
                dv4[0] = d.x; dv4[1] = d.y; dv4[2] = d.z; dv4[3] = d.w;
            }
#pragma unroll
            for (int i = 0; i < 4; ++i)
#pragma unroll
                for (int j = 0; j < 4; ++j) {
                    acc1[i][j] += av4[i] * bv4[j];
                    if (!FIRST) acc2[i][j] += dv4[i] * b2v4[j];
                }
        }
        __syncthreads();
    }

#pragma unroll
    for (int i = 0; i < 4; ++i) {
        int row = rowb + ty * 4 + i;
        float4 r;
        float rr[4];
#pragma unroll
        for (int j = 0; j < 4; ++j) {
            int col = colb + tx * 4 + j;
            float denom = FIRST ? csum[col] : (acc2[i][j] + csum[col]);
            float hb = acc1[i][j] + th[col];
            rr[j] = tanhf(SQ2PI * hb * rsqrtf(denom));
        }
        r.x = rr[0]; r.y = rr[1]; r.z = rr[2]; r.w = rr[3];
        *(float4*)&out[(size_t)row * H + colb + tx * 4] = r;
    }
}

// per-row final layer: hlastbar, logp, xcov diag, per-row loss & wrong
__global__ __launch_bounds__(64) void final_k(const float* __restrict__ x4bar,
                                              const float* __restrict__ wlast,
                                              const float* __restrict__ thlast,
                                              const int* __restrict__ target,
                                              float* __restrict__ o_hlastbar,
                                              float* __restrict__ o_logp,
                                              float* __restrict__ o_xcov,
                                              float* __restrict__ rowloss,
                                              float* __restrict__ rowwrong) {
    int m = blockIdx.x;
    int lane = threadIdx.x;
    float ah = 0.f, as = 0.f, ac = 0.f;
    for (int j = lane; j < H; j += 64) {
        float x4 = x4bar[(size_t)m * H + j];
        float ml = tanhf(0.5f * wlast[j]);
        float d4 = 1.f - x4 * x4;
        float ml2 = ml * ml;
        ah += x4 * ml;
        as += d4 * ml2;
        ac += 1.f - ml2;
        o_xcov[(size_t)m * H * H + (size_t)j * (H + 1)] = d4;
    }
#pragma unroll
    for (int off = 32; off; off >>= 1) {
        ah += __shfl_down(ah, off);
        as += __shfl_down(as, off);
        ac += __shfl_down(ac, off);
    }
    if (lane == 0) {
        float hb = ah + thlast[0];
        float ds = as + ac;
        float h = SQ2PI * hb * rsqrtf(ds);
        float lp = (h >= 0.f) ? -log1pf(expf(-h)) : (h - log1pf(expf(h)));
        float hn = -h;
        float lq = (hn >= 0.f) ? -log1pf(expf(-hn)) : (hn - log1pf(expf(hn)));
        o_hlastbar[m] = hb;
        o_logp[m] = lp;
        float y = (float)target[m];
        rowloss[m] = y * lp + (1.f - y) * lq;
        float pred = (h > 0.f) ? 1.f : 0.f;
        rowwrong[m] = fabsf(pred - y);
    }
}

__global__ __launch_bounds__(256) void reduce_k(const float* __restrict__ rowloss,
                                                const float* __restrict__ rowwrong,
                                                float* __restrict__ o_loss,
                                                float* __restrict__ o_frac) {
    __shared__ float sl[256], sw[256];
    int t = threadIdx.x;
    sl[t] = rowloss[t] + rowloss[t + 256];
    sw[t] = rowwrong[t] + rowwrong[t + 256];
    __syncthreads();
    for (int off = 128; off; off >>= 1) {
        if (t < off) { sl[t] += sl[t + off]; sw[t] += sw[t + off]; }
        __syncthreads();
    }
    if (t == 0) {
        *o_loss = -sl[0] / (float)MB;
        *o_frac = ((float)MB - sw[0]) / (float)MB;
    }
}

extern "C" void kernel_launch(void* const* d_in, const int* in_sizes, int n_in,
                              void* d_out, int out_size, void* d_ws, size_t ws_size,
                              hipStream_t stream) {
    const float* x = (const float*)d_in[0];
    const float* w0 = (const float*)d_in[1];
    const float* w1 = (const float*)d_in[2];
    const float* w2 = (const float*)d_in[3];
    const float* w3 = (const float*)d_in[4];
    // d_in[5] (w4) unused by the reference
    const float* wlast = (const float*)d_in[6];
    const float* th0 = (const float*)d_in[7];
    const float* th1 = (const float*)d_in[8];
    const float* th2 = (const float*)d_in[9];
    const float* th3 = (const float*)d_in[10];
    // d_in[11] (th4) unused
    const float* thlast = (const float*)d_in[12];
    const int* target = (const int*)d_in[13];

    float* ws = (float*)d_ws;
    float* m0 = ws;                       // 784*512
    float* m1 = m0 + DIN * H;             // 512*512
    float* m2 = m1 + H * H;
    float* m3 = m2 + H * H;
    float* c0 = m3 + H * H;               // 512 each
    float* c1 = c0 + H;
    float* c2 = c1 + H;
    float* c3 = c2 + H;
    float* x1b = c3 + H;                  // 512*512 each
    float* x2b = x1b + MB * H;
    float* x3b = x2b + MB * H;
    float* x4b = x3b + MB * H;
    float* rowloss = x4b + MB * H;        // 512
    float* rowwrong = rowloss + MB;       // 512

    float* out = (float*)d_out;
    float* o_hlastbar = out;              // 512
    float* o_logp = out + MB;             // 512
    float* o_xcov = out + 2 * MB;         // 512^3
    float* o_loss = o_xcov + XCOV_ELEMS;  // 1
    float* o_frac = o_loss + 1;           // 1

    wtrans_k<<<2, 256, 0, stream>>>(w0, m0, c0, DIN);
    wtrans_k<<<2, 256, 0, stream>>>(w1, m1, c1, H);
    wtrans_k<<<2, 256, 0, stream>>>(w2, m2, c2, H);
    wtrans_k<<<2, 256, 0, stream>>>(w3, m3, c3, H);

    hipMemsetAsync(o_xcov, 0, XCOV_ELEMS * sizeof(float), stream);

    dim3 grid(H / 64, MB / 64);
    layer_k<true><<<grid, 256, 0, stream>>>(x, nullptr, m0, c0, th0, x1b, DIN);
    layer_k<false><<<grid, 256, 0, stream>>>(x1b, x1b, m1, c1, th1, x2b, H);
    layer_k<false><<<grid, 256, 0, stream>>>(x2b, x2b, m2, c2, th2, x3b, H);
    layer_k<false><<<grid, 256, 0, stream>>>(x3b, x2b, m3, c3, th3, x4b, H);

    final_k<<<MB, 64, 0, stream>>>(x4b, wlast, thlast, target,
                                   o_hlastbar, o_logp, o_xcov, rowloss, rowwrong);
    reduce_k<<<1, 256, 0, stream>>>(rowloss, rowwrong, o_loss, o_frac);
}

// Round 2
// 486.068 us; speedup vs baseline: 3.1391x; 3.1391x over previous
//
#include <hip/hip_runtime.h>
#include <math.h>

#define SQ2PI 0.79788456f
#define H 512
#define MB 512
#define DIN 784
#define XCOV_ELEMS ((size_t)MB * H * H)

// Fused m/c computation for all four weight matrices.
// Grid: 4 matrices x 8 column-tiles of 64. Block: 256 = 4 rowgroups x 64 cols.
// m = tanh(w/2); c[j] = rows - sum_i m[i][j]^2
__global__ __launch_bounds__(256) void wtrans4_k(
    const float* __restrict__ w0, float* __restrict__ m0, float* __restrict__ c0,
    const float* __restrict__ w1, float* __restrict__ m1, float* __restrict__ c1,
    const float* __restrict__ w2, float* __restrict__ m2, float* __restrict__ c2,
    const float* __restrict__ w3, float* __restrict__ m3, float* __restrict__ c3) {
    __shared__ float sm[256];
    const int mat = blockIdx.x >> 3;
    const int colb = (blockIdx.x & 7) * 64;
    const float* w; float* m; float* c; int rows;
    switch (mat) {
        case 0: w = w0; m = m0; c = c0; rows = DIN; break;
        case 1: w = w1; m = m1; c = c1; rows = H; break;
        case 2: w = w2; m = m2; c = c2; rows = H; break;
        default: w = w3; m = m3; c = c3; rows = H; break;
    }
    const int lane = threadIdx.x & 63;
    const int rowg = threadIdx.x >> 6;
    const int col = colb + lane;
    float acc = 0.f;
    for (int i = rowg; i < rows; i += 4) {
        float v = tanhf(0.5f * w[(size_t)i * H + col]);
        m[(size_t)i * H + col] = v;
        acc += v * v;
    }
    sm[threadIdx.x] = acc;
    __syncthreads();
    if (threadIdx.x < 64) {
        float s = sm[threadIdx.x] + sm[threadIdx.x + 64] +
                  sm[threadIdx.x + 128] + sm[threadIdx.x + 192];
        c[colb + threadIdx.x] = (float)rows - s;
    }
}

// out[r][c] = tanh(SQ2PI * (A@W + th) * rsqrt( (FIRST? 0 : (1-Dsrc^2)@W^2) + csum ))
// A: M x K, Dsrc: M x K (ignored if FIRST), W: K x 512
template <bool FIRST>
__global__ __launch_bounds__(256) void layer_k(const float* __restrict__ A,
                                               const float* __restrict__ Dsrc,
                                               const float* __restrict__ W,
                                               const float* __restrict__ csum,
                                               const float* __restrict__ th,
                                               float* __restrict__ out,
                                               int K) {
    __shared__ __align__(16) float As[16][64];
    __shared__ __align__(16) float Ds[16][64];
    __shared__ __align__(16) float Bs[16][64];
    __shared__ __align__(16) float B2s[16][64];

    const int tid = threadIdx.x;
    const int tx = tid & 15;          // col group
    const int ty = tid >> 4;          // row group
    const int rowb = blockIdx.y * 64;
    const int colb = blockIdx.x * 64;

    float acc1[4][4] = {};
    float acc2[4][4] = {};

    const int lrow = tid >> 2;        // 0..63
    const int kseg = (tid & 3) * 4;   // 0,4,8,12

    for (int k0 = 0; k0 < K; k0 += 16) {
        float4 av = *(const float4*)&A[(size_t)(rowb + lrow) * K + k0 + kseg];
        As[kseg + 0][lrow] = av.x;
        As[kseg + 1][lrow] = av.y;
        As[kseg + 2][lrow] = av.z;
        As[kseg + 3][lrow] = av.w;
        if (!FIRST) {
            float4 dv = *(const float4*)&Dsrc[(size_t)(rowb + lrow) * K + k0 + kseg];
            Ds[kseg + 0][lrow] = 1.f - dv.x * dv.x;
            Ds[kseg + 1][lrow] = 1.f - dv.y * dv.y;
            Ds[kseg + 2][lrow] = 1.f - dv.z * dv.z;
            Ds[kseg + 3][lrow] = 1.f - dv.w * dv.w;
        }
#pragma unroll
        for (int i = 0; i < 4; ++i) {
            int e = tid + i * 256;
            int kk = e >> 6, col = e & 63;
            float v = W[(size_t)(k0 + kk) * H + colb + col];
            Bs[kk][col] = v;
            B2s[kk][col] = v * v;
        }
        __syncthreads();

#pragma unroll
        for (int kk = 0; kk < 16; ++kk) {
            float4 a = *(const float4*)&As[kk][ty * 4];
            float4 b = *(const float4*)&Bs[kk][tx * 4];
            float4 b2 = *(const float4*)&B2s[kk][tx * 4];
            float av4[4] = {a.x, a.y, a.z, a.w};
            float bv4[4] = {b.x, b.y, b.z, b.w};
            float b2v4[4] = {b2.x, b2.y, b2.z, b2.w};
            float dv4[4];
            if (!FIRST) {
                float4 d = *(const float4*)&Ds[kk][ty * 4];
                dv4[0] = d.x; dv4[1] = d.y; dv4[2] = d.z; dv4[3] = d.w;
            }
#pragma unroll
            for (int i = 0; i < 4; ++i)
#pragma unroll
                for (int j = 0; j < 4; ++j) {
                    acc1[i][j] += av4[i] * bv4[j];
                    if (!FIRST) acc2[i][j] += dv4[i] * b2v4[j];
                }
        }
        __syncthreads();
    }

#pragma unroll
    for (int i = 0; i < 4; ++i) {
        int row = rowb + ty * 4 + i;
        float4 r;
        float rr[4];
#pragma unroll
        for (int j = 0; j < 4; ++j) {
            int col = colb + tx * 4 + j;
            float denom = FIRST ? csum[col] : (acc2[i][j] + csum[col]);
            float hb = acc1[i][j] + th[col];
            rr[j] = tanhf(SQ2PI * hb * rsqrtf(denom));
        }
        r.x = rr[0]; r.y = rr[1]; r.z = rr[2]; r.w = rr[3];
        *(float4*)&out[(size_t)row * H + colb + tx * 4] = r;
    }
}

// per-row final layer: hlastbar, logp, xcov diag, per-row loss & wrong
__global__ __launch_bounds__(64) void final_k(const float* __restrict__ x4bar,
                                              const float* __restrict__ wlast,
                                              const float* __restrict__ thlast,
                                              const int* __restrict__ target,
                                              float* __restrict__ o_hlastbar,
                                              float* __restrict__ o_logp,
                                              float* __restrict__ o_xcov,
                                              float* __restrict__ rowloss,
                                              float* __restrict__ rowwrong) {
    int m = blockIdx.x;
    int lane = threadIdx.x;
    float ah = 0.f, as = 0.f, ac = 0.f;
    for (int j = lane; j < H; j += 64) {
        float x4 = x4bar[(size_t)m * H + j];
        float ml = tanhf(0.5f * wlast[j]);
        float d4 = 1.f - x4 * x4;
        float ml2 = ml * ml;
        ah += x4 * ml;
        as += d4 * ml2;
        ac += 1.f - ml2;
        o_xcov[(size_t)m * H * H + (size_t)j * (H + 1)] = d4;
    }
#pragma unroll
    for (int off = 32; off; off >>= 1) {
        ah += __shfl_down(ah, off);
        as += __shfl_down(as, off);
        ac += __shfl_down(ac, off);
    }
    if (lane == 0) {
        float hb = ah + thlast[0];
        float ds = as + ac;
        float h = SQ2PI * hb * rsqrtf(ds);
        float lp = (h >= 0.f) ? -log1pf(expf(-h)) : (h - log1pf(expf(h)));
        float hn = -h;
        float lq = (hn >= 0.f) ? -log1pf(expf(-hn)) : (hn - log1pf(expf(hn)));
        o_hlastbar[m] = hb;
        o_logp[m] = lp;
        float y = (float)target[m];
        rowloss[m] = y * lp + (1.f - y) * lq;
        float pred = (h > 0.f) ? 1.f : 0.f;
        rowwrong[m] = fabsf(pred - y);
    }
}

__global__ __launch_bounds__(256) void reduce_k(const float* __restrict__ rowloss,
                                                const float* __restrict__ rowwrong,
                                                float* __restrict__ o_loss,
                                                float* __restrict__ o_frac) {
    __shared__ float sl[256], sw[256];
    int t = threadIdx.x;
    sl[t] = rowloss[t] + rowloss[t + 256];
    sw[t] = rowwrong[t] + rowwrong[t + 256];
    __syncthreads();
    for (int off = 128; off; off >>= 1) {
        if (t < off) { sl[t] += sl[t + off]; sw[t] += sw[t + off]; }
        __syncthreads();
    }
    if (t == 0) {
        *o_loss = -sl[0] / (float)MB;
        *o_frac = ((float)MB - sw[0]) / (float)MB;
    }
}

extern "C" void kernel_launch(void* const* d_in, const int* in_sizes, int n_in,
                              void* d_out, int out_size, void* d_ws, size_t ws_size,
                              hipStream_t stream) {
    const float* x = (const float*)d_in[0];
    const float* w0 = (const float*)d_in[1];
    const float* w1 = (const float*)d_in[2];
    const float* w2 = (const float*)d_in[3];
    const float* w3 = (const float*)d_in[4];
    // d_in[5] (w4) unused by the reference
    const float* wlast = (const float*)d_in[6];
    const float* th0 = (const float*)d_in[7];
    const float* th1 = (const float*)d_in[8];
    const float* th2 = (const float*)d_in[9];
    const float* th3 = (const float*)d_in[10];
    // d_in[11] (th4) unused
    const float* thlast = (const float*)d_in[12];
    const int* target = (const int*)d_in[13];

    float* ws = (float*)d_ws;
    float* m0 = ws;                       // 784*512
    float* m1 = m0 + DIN * H;             // 512*512
    float* m2 = m1 + H * H;
    float* m3 = m2 + H * H;
    float* c0 = m3 + H * H;               // 512 each
    float* c1 = c0 + H;
    float* c2 = c1 + H;
    float* c3 = c2 + H;
    float* x1b = c3 + H;                  // 512*512 each
    float* x2b = x1b + MB * H;
    float* x3b = x2b + MB * H;
    float* x4b = x3b + MB * H;
    float* rowloss = x4b + MB * H;        // 512
    float* rowwrong = rowloss + MB;       // 512

    float* out = (float*)d_out;
    float* o_hlastbar = out;              // 512
    float* o_logp = out + MB;             // 512
    float* o_xcov = out + 2 * MB;         // 512^3
    float* o_loss = o_xcov + XCOV_ELEMS;  // 1
    float* o_frac = o_loss + 1;           // 1

    hipMemsetAsync(o_xcov, 0, XCOV_ELEMS * sizeof(float), stream);

    wtrans4_k<<<32, 256, 0, stream>>>(w0, m0, c0, w1, m1, c1,
                                      w2, m2, c2, w3, m3, c3);

    dim3 grid(H / 64, MB / 64);
    layer_k<true><<<grid, 256, 0, stream>>>(x, nullptr, m0, c0, th0, x1b, DIN);
    layer_k<false><<<grid, 256, 0, stream>>>(x1b, x1b, m1, c1, th1, x2b, H);
    layer_k<false><<<grid, 256, 0, stream>>>(x2b, x2b, m2, c2, th2, x3b, H);
    layer_k<false><<<grid, 256, 0, stream>>>(x3b, x2b, m3, c3, th3, x4b, H);

    final_k<<<MB, 64, 0, stream>>>(x4b, wlast, thlast, target,
                                   o_hlastbar, o_logp, o_xcov, rowloss, rowwrong);
    reduce_k<<<1, 256, 0, stream>>>(rowloss, rowwrong, o_loss, o_frac);
}